// Round 1
// baseline (58046.484 us; speedup 1.0000x reference)
//
#include <hip/hip_runtime.h>
#include <hip/hip_cooperative_groups.h>
#include <cstddef>

namespace cg = cooperative_groups;

// Problem constants (B,S,D,H,L) = (32,512,1024,1024,2); D==H==1024 so both
// layers' projections share K=1024.
#define Bq 32
#define Sq 512
#define Hq 1024
#define G4q 4096          // 4*H
#define CHUNKq 128        // timesteps per gates chunk
#define NCHq (Sq / CHUNKq)
#define BHq (Bq * Hq)     // 32768

// ---------------------------------------------------------------------------
// Input-projection GEMM: gates[r][b][n] = sum_k A[(b,s0+r)][k] * W[k][n] + bias[n]
// A rows are (b, s) from a [B,S,1024] tensor. C tile 128x128, 256 threads,
// 8x8 per thread, BK=8, LDS staged (A transposed in LDS for b128 reads).
// ---------------------------------------------------------------------------
__global__ __launch_bounds__(256)
void gemm_xproj(const float* __restrict__ A,
                const float* __restrict__ Wm,
                const float* __restrict__ bias,
                float* __restrict__ gates,
                int s0)
{
    __shared__ float As[8][132];   // [k][m] transposed
    __shared__ float Bs[8][132];   // [k][n]

    const int tid = threadIdx.x;
    const int tr = tid >> 4;       // 0..15
    const int tc = tid & 15;       // 0..15
    const int m0 = blockIdx.y * 128;
    const int n0 = blockIdx.x * 128;

    float acc[8][8];
    #pragma unroll
    for (int i = 0; i < 8; ++i)
        #pragma unroll
        for (int j = 0; j < 8; ++j) acc[i][j] = 0.f;

    // global staging indices
    const int a_m  = tid >> 1;           // 0..127
    const int a_k4 = (tid & 1) * 4;      // 0 or 4
    const int b_k  = tid >> 5;           // 0..7
    const int b_n4 = (tid & 31) * 4;     // 0..124

    const int am_g = m0 + a_m;
    const int ab = am_g >> 7;            // batch  (CHUNK=128)
    const int as = s0 + (am_g & 127);    // seq pos
    const float* Arow = A + ((size_t)ab * Sq + as) * 1024;

    for (int k0 = 0; k0 < 1024; k0 += 8) {
        float4 av = *(const float4*)(Arow + k0 + a_k4);
        float4 bv = *(const float4*)(Wm + (size_t)(k0 + b_k) * G4q + n0 + b_n4);
        __syncthreads();   // previous iteration's reads done
        As[a_k4 + 0][a_m] = av.x;
        As[a_k4 + 1][a_m] = av.y;
        As[a_k4 + 2][a_m] = av.z;
        As[a_k4 + 3][a_m] = av.w;
        *(float4*)(&Bs[b_k][b_n4]) = bv;
        __syncthreads();
        #pragma unroll
        for (int kk = 0; kk < 8; ++kk) {
            float4 a0 = *(const float4*)(&As[kk][tr * 8]);
            float4 a1 = *(const float4*)(&As[kk][tr * 8 + 4]);
            float4 b0 = *(const float4*)(&Bs[kk][tc * 8]);
            float4 b1 = *(const float4*)(&Bs[kk][tc * 8 + 4]);
            float avv[8] = {a0.x, a0.y, a0.z, a0.w, a1.x, a1.y, a1.z, a1.w};
            float bvv[8] = {b0.x, b0.y, b0.z, b0.w, b1.x, b1.y, b1.z, b1.w};
            #pragma unroll
            for (int i = 0; i < 8; ++i)
                #pragma unroll
                for (int j = 0; j < 8; ++j)
                    acc[i][j] += avv[i] * bvv[j];
        }
    }

    float bv8[8];
    *(float4*)(bv8)     = *(const float4*)(bias + n0 + tc * 8);
    *(float4*)(bv8 + 4) = *(const float4*)(bias + n0 + tc * 8 + 4);

    #pragma unroll
    for (int i = 0; i < 8; ++i) {
        const int m = m0 + tr * 8 + i;
        const int b = m >> 7;
        const int r = m & 127;
        float* outp = gates + ((size_t)r * Bq + b) * G4q + n0 + tc * 8;
        float4 v0 = {acc[i][0] + bv8[0], acc[i][1] + bv8[1],
                     acc[i][2] + bv8[2], acc[i][3] + bv8[3]};
        float4 v1 = {acc[i][4] + bv8[4], acc[i][5] + bv8[5],
                     acc[i][6] + bv8[6], acc[i][7] + bv8[7]};
        *(float4*)outp       = v0;
        *(float4*)(outp + 4) = v1;
    }
}

// ---------------------------------------------------------------------------
// Cooperative scan. 256 blocks x 512 threads, one grid.sync per timestep.
// Block cg owns cells j0=cg*4..+4 (all 32 batches) -> self-contained c/h
// update (gate g for cell j sits at col p*H + j, p=0..3).
// Thread = (ks 0..31) x (bg 0..3) x (ct 0..3): partial over k-slice of 32 for
// 8 batches x 4 cols (one gate type). h kept TRANSPOSED [H][B] so h loads are
// 2x float4. Reduction: shfl over 4 ks/wave, then LDS over 8 waves.
// c stays in registers across the whole chunk.
// ---------------------------------------------------------------------------
__device__ __forceinline__ float wave_red4(float v) {
    v += __shfl_xor(v, 16, 64);
    v += __shfl_xor(v, 32, 64);
    return v;
}

__global__ __launch_bounds__(512)
void lstm_scan(const float* __restrict__ gates,
               const float* __restrict__ Whh,
               float* __restrict__ hbuf,     // [2][H][B] transposed, dbuf
               float* __restrict__ cstate,   // [B][H]
               float* __restrict__ y,        // [B][S][H]
               int t0)
{
    cg::grid_group grid = cg::this_grid();
    __shared__ float part[8][16][32];

    const int tid = threadIdx.x;
    const int ks  = tid >> 4;        // 0..31
    const int sub = tid & 15;
    const int bg  = sub >> 2;        // 0..3  (8 batches each)
    const int ct  = sub & 3;         // gate type
    const int wv  = tid >> 6;        // 0..7
    const int j0  = blockIdx.x * 4;
    const int col = ct * Hq + j0;
    const int kbase = ks * 32;

    const int ub = tid >> 2, ujj = tid & 3;   // update-thread mapping (tid<128)
    float creg = 0.f;
    if (tid < 128) creg = cstate[ub * Hq + j0 + ujj];

    for (int tt = 0; tt < CHUNKq; ++tt) {
        const float* ht = hbuf + (tt & 1) * BHq;
        float* hw = hbuf + ((tt + 1) & 1) * BHq;

        float4 acc[8];
        #pragma unroll
        for (int r = 0; r < 8; ++r) acc[r] = make_float4(0.f, 0.f, 0.f, 0.f);

        const float* hp = ht + kbase * Bq + bg * 8;
        const float* wp = Whh + (size_t)kbase * G4q + col;
        #pragma unroll 4
        for (int kk = 0; kk < 32; ++kk) {
            float4 w4 = *(const float4*)wp;
            float4 ha = *(const float4*)hp;
            float4 hb = *(const float4*)(hp + 4);
            wp += G4q;
            hp += Bq;
            float hv8[8] = {ha.x, ha.y, ha.z, ha.w, hb.x, hb.y, hb.z, hb.w};
            #pragma unroll
            for (int r = 0; r < 8; ++r) {
                const float hv = hv8[r];
                acc[r].x += hv * w4.x;
                acc[r].y += hv * w4.y;
                acc[r].z += hv * w4.z;
                acc[r].w += hv * w4.w;
            }
        }

        #pragma unroll
        for (int r = 0; r < 8; ++r) {
            acc[r].x = wave_red4(acc[r].x);
            acc[r].y = wave_red4(acc[r].y);
            acc[r].z = wave_red4(acc[r].z);
            acc[r].w = wave_red4(acc[r].w);
        }
        if ((tid & 48) == 0) {            // lane%64 < 16: one lane per sub/wave
            #pragma unroll
            for (int r = 0; r < 8; ++r)
                *(float4*)(&part[wv][sub][r * 4]) = acc[r];
        }
        __syncthreads();

        if (tid < 128) {
            const float* gin = gates + ((size_t)tt * Bq + ub) * G4q + j0 + ujj;
            const int ps = (ub >> 3) * 4;
            const int pi = (ub & 7) * 4 + ujj;
            float g[4];
            #pragma unroll
            for (int p = 0; p < 4; ++p) {
                float s = 0.f;
                #pragma unroll
                for (int w = 0; w < 8; ++w) s += part[w][ps + p][pi];
                g[p] = s + gin[p * Hq];
            }
            const float iv = 1.f / (1.f + expf(-g[0]));
            const float fv = 1.f / (1.f + expf(-g[1]));
            const float gv = tanhf(g[2]);
            const float ov = 1.f / (1.f + expf(-g[3]));
            creg = fv * creg + iv * gv;
            const float hv = ov * tanhf(creg);
            hw[(j0 + ujj) * Bq + ub] = hv;                      // transposed h
            y[((size_t)ub * Sq + (t0 + tt)) * Hq + j0 + ujj] = hv;
        }
        grid.sync();   // h(t) visible everywhere; also orders LDS reuse
    }
    if (tid < 128) cstate[ub * Hq + j0 + ujj] = creg;
}

// ---------------------------------------------------------------------------
// tiny state-layout shims: [B][H] <-> transposed [H][B]
// ---------------------------------------------------------------------------
__global__ __launch_bounds__(256)
void h_to_t(const float* __restrict__ src, float* __restrict__ dst) {
    const int i = blockIdx.x * 256 + threadIdx.x;   // 0..32767
    const int b = i >> 10, j = i & 1023;
    dst[j * Bq + b] = src[i];
}
__global__ __launch_bounds__(256)
void h_from_t(const float* __restrict__ src, float* __restrict__ dst) {
    const int i = blockIdx.x * 256 + threadIdx.x;
    const int b = i >> 10, j = i & 1023;
    dst[i] = src[j * Bq + b];
}

// ---------------------------------------------------------------------------
extern "C" void kernel_launch(void* const* d_in, const int* in_sizes, int n_in,
                              void* d_out, int out_size, void* d_ws, size_t ws_size,
                              hipStream_t stream)
{
    const float* x    = (const float*)d_in[0];
    const float* h0   = (const float*)d_in[1];
    const float* c0   = (const float*)d_in[2];
    const float* wih0 = (const float*)d_in[3];
    const float* whh0 = (const float*)d_in[4];
    const float* b0   = (const float*)d_in[5];
    const float* wih1 = (const float*)d_in[6];
    const float* whh1 = (const float*)d_in[7];
    const float* b1   = (const float*)d_in[8];

    float* out = (float*)d_out;
    float* y1  = out;                                  // [B,S,H]
    float* hn  = out + (size_t)Bq * Sq * Hq;           // [2,B,H]
    float* cn  = hn + 2 * BHq;                         // [2,B,H]

    float* ws    = (float*)d_ws;
    float* gates = ws;                                  // CHUNK*B*4H floats (64MB)
    float* hbuf  = gates + (size_t)CHUNKq * Bq * G4q;   // 2*B*H
    float* cst   = hbuf + 2 * BHq;                      // B*H

    // y0 aliases the y1 output region: layer-1 GEMM chunk ch reads y0 rows of
    // chunk ch strictly before layer-1 scan chunk ch overwrites those rows.
    float* y0 = y1;

    for (int l = 0; l < 2; ++l) {
        const float* Ain  = l ? y0   : x;
        const float* wih  = l ? wih1 : wih0;
        const float* whh  = l ? whh1 : whh0;
        const float* bias = l ? b1   : b0;
        float* yout       = l ? y1   : y0;

        h_to_t<<<128, 256, 0, stream>>>(h0 + (size_t)l * BHq, hbuf);
        hipMemcpyAsync(cst, c0 + (size_t)l * BHq, BHq * sizeof(float),
                       hipMemcpyDeviceToDevice, stream);

        for (int ch = 0; ch < NCHq; ++ch) {
            const int s0 = ch * CHUNKq;
            gemm_xproj<<<dim3(32, 32), 256, 0, stream>>>(Ain, wih, bias, gates, s0);

            const float* garg = gates;
            const float* warg = whh;
            float* harg = hbuf;
            float* carg = cst;
            float* yarg = yout;
            int targ = s0;
            void* kp[] = {(void*)&garg, (void*)&warg, (void*)&harg,
                          (void*)&carg, (void*)&yarg, (void*)&targ};
            hipLaunchCooperativeKernel((void*)lstm_scan, dim3(256), dim3(512),
                                       kp, 0, stream);
        }

        h_from_t<<<128, 256, 0, stream>>>(hbuf, hn + (size_t)l * BHq);
        hipMemcpyAsync(cn + (size_t)l * BHq, cst, BHq * sizeof(float),
                       hipMemcpyDeviceToDevice, stream);
    }
}

// Round 4
// 41670.636 us; speedup vs baseline: 1.3930x; 1.3930x over previous
//
#include <hip/hip_runtime.h>
#include <hip/hip_cooperative_groups.h>
#include <cstddef>

namespace cg = cooperative_groups;

// Problem constants (B,S,D,H,L) = (32,512,1024,1024,2); D==H==1024 so both
// layers' projections share K=1024.
#define Bq 32
#define Sq 512
#define Hq 1024
#define G4q 4096          // 4*H
#define CHUNKq 128        // timesteps per gates chunk
#define NCHq (Sq / CHUNKq)
#define BHq (Bq * Hq)     // 32768

// ---------------------------------------------------------------------------
// Input-projection GEMM: gates[r][b][n] = sum_k A[(b,s0+r)][k] * W[k][n] + bias[n]
// A rows are (b, s) from a [B,S,1024] tensor. C tile 128x128, 256 threads,
// 8x8 per thread, BK=8, LDS staged (A transposed in LDS for b128 reads).
// ---------------------------------------------------------------------------
__global__ __launch_bounds__(256)
void gemm_xproj(const float* __restrict__ A,
                const float* __restrict__ Wm,
                const float* __restrict__ bias,
                float* __restrict__ gates,
                int s0)
{
    __shared__ float As[8][132];   // [k][m] transposed
    __shared__ float Bs[8][132];   // [k][n]

    const int tid = threadIdx.x;
    const int tr = tid >> 4;       // 0..15
    const int tc = tid & 15;       // 0..15
    const int m0 = blockIdx.y * 128;
    const int n0 = blockIdx.x * 128;

    float acc[8][8];
    #pragma unroll
    for (int i = 0; i < 8; ++i)
        #pragma unroll
        for (int j = 0; j < 8; ++j) acc[i][j] = 0.f;

    // global staging indices
    const int a_m  = tid >> 1;           // 0..127
    const int a_k4 = (tid & 1) * 4;      // 0 or 4
    const int b_k  = tid >> 5;           // 0..7
    const int b_n4 = (tid & 31) * 4;     // 0..124

    const int am_g = m0 + a_m;
    const int ab = am_g >> 7;            // batch  (CHUNK=128)
    const int as = s0 + (am_g & 127);    // seq pos
    const float* Arow = A + ((size_t)ab * Sq + as) * 1024;

    for (int k0 = 0; k0 < 1024; k0 += 8) {
        float4 av = *(const float4*)(Arow + k0 + a_k4);
        float4 bv = *(const float4*)(Wm + (size_t)(k0 + b_k) * G4q + n0 + b_n4);
        __syncthreads();   // previous iteration's reads done
        As[a_k4 + 0][a_m] = av.x;
        As[a_k4 + 1][a_m] = av.y;
        As[a_k4 + 2][a_m] = av.z;
        As[a_k4 + 3][a_m] = av.w;
        *(float4*)(&Bs[b_k][b_n4]) = bv;
        __syncthreads();
        #pragma unroll
        for (int kk = 0; kk < 8; ++kk) {
            float4 a0 = *(const float4*)(&As[kk][tr * 8]);
            float4 a1 = *(const float4*)(&As[kk][tr * 8 + 4]);
            float4 b0 = *(const float4*)(&Bs[kk][tc * 8]);
            float4 b1 = *(const float4*)(&Bs[kk][tc * 8 + 4]);
            float avv[8] = {a0.x, a0.y, a0.z, a0.w, a1.x, a1.y, a1.z, a1.w};
            float bvv[8] = {b0.x, b0.y, b0.z, b0.w, b1.x, b1.y, b1.z, b1.w};
            #pragma unroll
            for (int i = 0; i < 8; ++i)
                #pragma unroll
                for (int j = 0; j < 8; ++j)
                    acc[i][j] += avv[i] * bvv[j];
        }
    }

    float bv8[8];
    *(float4*)(bv8)     = *(const float4*)(bias + n0 + tc * 8);
    *(float4*)(bv8 + 4) = *(const float4*)(bias + n0 + tc * 8 + 4);

    #pragma unroll
    for (int i = 0; i < 8; ++i) {
        const int m = m0 + tr * 8 + i;
        const int b = m >> 7;
        const int r = m & 127;
        float* outp = gates + ((size_t)r * Bq + b) * G4q + n0 + tc * 8;
        float4 v0 = {acc[i][0] + bv8[0], acc[i][1] + bv8[1],
                     acc[i][2] + bv8[2], acc[i][3] + bv8[3]};
        float4 v1 = {acc[i][4] + bv8[4], acc[i][5] + bv8[5],
                     acc[i][6] + bv8[6], acc[i][7] + bv8[7]};
        *(float4*)outp       = v0;
        *(float4*)(outp + 4) = v1;
    }
}

// ---------------------------------------------------------------------------
// Cooperative scan. 256 blocks x 512 threads, one grid.sync per timestep.
// Block cg owns cells j0=cg*4..+4 (all 32 batches).
//
// KEY CHANGE (R1, measuring this round): each block's 16 Whh columns
// (4 cells x 4 gate types, 1024 k) are staged into LDS ONCE per dispatch
// (64 KB). Previously every timestep refetched Whh from HBM (grid.sync's
// acquire fence invalidates per-XCD L2, and 128B lines interleave 8 blocks'
// columns across XCDs): FETCH_SIZE was 8.9 GB/dispatch == the entire
// 6.74 ms at 1.33 TB/s. LDS staging makes Whh traffic one-shot (16.8 MB).
//
// Thread = (ks 0..31) x (bg 0..3) x (ct 0..3): partial over k-slice of 32 for
// 8 batches x 4 cols (one gate type). h kept TRANSPOSED [H][B] so h loads are
// 2x float4. Reduction: shfl over 4 ks/wave, then LDS over 8 waves.
// c stays in registers across the whole chunk.
// LDS: 64 KB Wlds + 16 KB part = 80 KB -> 1 block/CU (160 KB available).
// ---------------------------------------------------------------------------
__device__ __forceinline__ float wave_red4(float v) {
    v += __shfl_xor(v, 16, 64);
    v += __shfl_xor(v, 32, 64);
    return v;
}

__global__ __launch_bounds__(512)
void lstm_scan(const float* __restrict__ gates,
               const float* __restrict__ Whh,
               float* __restrict__ hbuf,     // [2][H][B] transposed, dbuf
               float* __restrict__ cstate,   // [B][H]
               float* __restrict__ y,        // [B][S][H]
               int t0)
{
    cg::grid_group grid = cg::this_grid();
    __shared__ float Wlds[1024][16];   // [k][ct*4 + jj]  (64 KB)
    __shared__ float part[8][16][32];  // 16 KB

    const int tid = threadIdx.x;
    const int ks  = tid >> 4;        // 0..31
    const int sub = tid & 15;
    const int bg  = sub >> 2;        // 0..3  (8 batches each)
    const int ct  = sub & 3;         // gate type
    const int wv  = tid >> 6;        // 0..7
    const int j0  = blockIdx.x * 4;
    const int kbase = ks * 32;

    // --- stage this block's 16 Whh columns into LDS (once per dispatch) ---
    #pragma unroll
    for (int idx = tid; idx < 4096; idx += 512) {
        const int k  = idx >> 2;
        const int c  = idx & 3;
        float4 w = *(const float4*)(Whh + (size_t)k * G4q + c * Hq + j0);
        *(float4*)(&Wlds[k][c * 4]) = w;
    }

    const int ub = tid >> 2, ujj = tid & 3;   // update-thread mapping (tid<128)
    float creg = 0.f;
    if (tid < 128) creg = cstate[ub * Hq + j0 + ujj];
    __syncthreads();

    for (int tt = 0; tt < CHUNKq; ++tt) {
        const float* ht = hbuf + (tt & 1) * BHq;
        float* hw = hbuf + ((tt + 1) & 1) * BHq;

        float4 acc[8];
        #pragma unroll
        for (int r = 0; r < 8; ++r) acc[r] = make_float4(0.f, 0.f, 0.f, 0.f);

        const float* hp = ht + kbase * Bq + bg * 8;
        const float* wp = &Wlds[kbase][ct * 4];
        #pragma unroll 4
        for (int kk = 0; kk < 32; ++kk) {
            float4 w4 = *(const float4*)wp;
            float4 ha = *(const float4*)hp;
            float4 hb = *(const float4*)(hp + 4);
            wp += 16;
            hp += Bq;
            float hv8[8] = {ha.x, ha.y, ha.z, ha.w, hb.x, hb.y, hb.z, hb.w};
            #pragma unroll
            for (int r = 0; r < 8; ++r) {
                const float hv = hv8[r];
                acc[r].x += hv * w4.x;
                acc[r].y += hv * w4.y;
                acc[r].z += hv * w4.z;
                acc[r].w += hv * w4.w;
            }
        }

        #pragma unroll
        for (int r = 0; r < 8; ++r) {
            acc[r].x = wave_red4(acc[r].x);
            acc[r].y = wave_red4(acc[r].y);
            acc[r].z = wave_red4(acc[r].z);
            acc[r].w = wave_red4(acc[r].w);
        }
        if ((tid & 48) == 0) {            // lane%64 < 16: one lane per sub/wave
            #pragma unroll
            for (int r = 0; r < 8; ++r)
                *(float4*)(&part[wv][sub][r * 4]) = acc[r];
        }
        __syncthreads();

        if (tid < 128) {
            const float* gin = gates + ((size_t)tt * Bq + ub) * G4q + j0 + ujj;
            const int ps = (ub >> 3) * 4;
            const int pi = (ub & 7) * 4 + ujj;
            float g[4];
            #pragma unroll
            for (int p = 0; p < 4; ++p) {
                float s = 0.f;
                #pragma unroll
                for (int w = 0; w < 8; ++w) s += part[w][ps + p][pi];
                g[p] = s + gin[p * Hq];
            }
            const float iv = 1.f / (1.f + expf(-g[0]));
            const float fv = 1.f / (1.f + expf(-g[1]));
            const float gv = tanhf(g[2]);
            const float ov = 1.f / (1.f + expf(-g[3]));
            creg = fv * creg + iv * gv;
            const float hv = ov * tanhf(creg);
            hw[(j0 + ujj) * Bq + ub] = hv;                      // transposed h
            y[((size_t)ub * Sq + (t0 + tt)) * Hq + j0 + ujj] = hv;
        }
        grid.sync();   // h(t) visible everywhere; also orders LDS reuse
    }
    if (tid < 128) cstate[ub * Hq + j0 + ujj] = creg;
}

// ---------------------------------------------------------------------------
// tiny state-layout shims: [B][H] <-> transposed [H][B]
// ---------------------------------------------------------------------------
__global__ __launch_bounds__(256)
void h_to_t(const float* __restrict__ src, float* __restrict__ dst) {
    const int i = blockIdx.x * 256 + threadIdx.x;   // 0..32767
    const int b = i >> 10, j = i & 1023;
    dst[j * Bq + b] = src[i];
}
__global__ __launch_bounds__(256)
void h_from_t(const float* __restrict__ src, float* __restrict__ dst) {
    const int i = blockIdx.x * 256 + threadIdx.x;
    const int b = i >> 10, j = i & 1023;
    dst[i] = src[j * Bq + b];
}

// ---------------------------------------------------------------------------
extern "C" void kernel_launch(void* const* d_in, const int* in_sizes, int n_in,
                              void* d_out, int out_size, void* d_ws, size_t ws_size,
                              hipStream_t stream)
{
    const float* x    = (const float*)d_in[0];
    const float* h0   = (const float*)d_in[1];
    const float* c0   = (const float*)d_in[2];
    const float* wih0 = (const float*)d_in[3];
    const float* whh0 = (const float*)d_in[4];
    const float* b0   = (const float*)d_in[5];
    const float* wih1 = (const float*)d_in[6];
    const float* whh1 = (const float*)d_in[7];
    const float* b1   = (const float*)d_in[8];

    float* out = (float*)d_out;
    float* y1  = out;                                  // [B,S,H]
    float* hn  = out + (size_t)Bq * Sq * Hq;           // [2,B,H]
    float* cn  = hn + 2 * BHq;                         // [2,B,H]

    float* ws    = (float*)d_ws;
    float* gates = ws;                                  // CHUNK*B*4H floats (64MB)
    float* hbuf  = gates + (size_t)CHUNKq * Bq * G4q;   // 2*B*H
    float* cst   = hbuf + 2 * BHq;                      // B*H

    // y0 aliases the y1 output region: layer-1 GEMM chunk ch reads y0 rows of
    // chunk ch strictly before layer-1 scan chunk ch overwrites those rows.
    float* y0 = y1;

    for (int l = 0; l < 2; ++l) {
        const float* Ain  = l ? y0   : x;
        const float* wih  = l ? wih1 : wih0;
        const float* whh  = l ? whh1 : whh0;
        const float* bias = l ? b1   : b0;
        float* yout       = l ? y1   : y0;

        h_to_t<<<128, 256, 0, stream>>>(h0 + (size_t)l * BHq, hbuf);
        hipMemcpyAsync(cst, c0 + (size_t)l * BHq, BHq * sizeof(float),
                       hipMemcpyDeviceToDevice, stream);

        for (int ch = 0; ch < NCHq; ++ch) {
            const int s0 = ch * CHUNKq;
            gemm_xproj<<<dim3(32, 32), 256, 0, stream>>>(Ain, wih, bias, gates, s0);

            const float* garg = gates;
            const float* warg = whh;
            float* harg = hbuf;
            float* carg = cst;
            float* yarg = yout;
            int targ = s0;
            void* kp[] = {(void*)&garg, (void*)&warg, (void*)&harg,
                          (void*)&carg, (void*)&yarg, (void*)&targ};
            hipLaunchCooperativeKernel((void*)lstm_scan, dim3(256), dim3(512),
                                       kp, 0, stream);
        }

        h_from_t<<<128, 256, 0, stream>>>(hbuf, hn + (size_t)l * BHq);
        hipMemcpyAsync(cn + (size_t)l * BHq, cst, BHq * sizeof(float),
                       hipMemcpyDeviceToDevice, stream);
    }
}

// Round 6
// 17951.346 us; speedup vs baseline: 3.2335x; 2.3213x over previous
//
#include <hip/hip_runtime.h>
#include <hip/hip_cooperative_groups.h>
#include <cstddef>

// Problem constants (B,S,D,H,L) = (32,512,1024,1024,2)
#define Bq 32
#define Sq 512
#define Hq 1024
#define G4q 4096          // 4*H
#define CHUNKq 128        // timesteps per gates chunk
#define NCHq (Sq / CHUNKq)
#define BHq (Bq * Hq)     // 32768

// ---------------------------------------------------------------------------
// Input-projection GEMM (R1 form; block(0,0) zeroes the scan's barrier words
// each chunk — ws is re-poisoned 0xAA before every launch, and this kernel
// always runs immediately before the scan on the same stream).
// ---------------------------------------------------------------------------
__global__ __launch_bounds__(256)
void gemm_xproj(const float* __restrict__ A,
                const float* __restrict__ Wm,
                const float* __restrict__ bias,
                float* __restrict__ gates,
                unsigned int* __restrict__ bar,
                int s0)
{
    __shared__ float As[8][132];   // [k][m] transposed
    __shared__ float Bs[8][132];   // [k][n]

    const int tid = threadIdx.x;
    if (blockIdx.x == 0 && blockIdx.y == 0 && tid < 18)
        bar[tid * 32] = 0u;        // 16 group counters + root + generation

    const int tr = tid >> 4;
    const int tc = tid & 15;
    const int m0 = blockIdx.y * 128;
    const int n0 = blockIdx.x * 128;

    float acc[8][8];
    #pragma unroll
    for (int i = 0; i < 8; ++i)
        #pragma unroll
        for (int j = 0; j < 8; ++j) acc[i][j] = 0.f;

    const int a_m  = tid >> 1;
    const int a_k4 = (tid & 1) * 4;
    const int b_k  = tid >> 5;
    const int b_n4 = (tid & 31) * 4;

    const int am_g = m0 + a_m;
    const int ab = am_g >> 7;
    const int as = s0 + (am_g & 127);
    const float* Arow = A + ((size_t)ab * Sq + as) * 1024;

    for (int k0 = 0; k0 < 1024; k0 += 8) {
        float4 av = *(const float4*)(Arow + k0 + a_k4);
        float4 bv = *(const float4*)(Wm + (size_t)(k0 + b_k) * G4q + n0 + b_n4);
        __syncthreads();
        As[a_k4 + 0][a_m] = av.x;
        As[a_k4 + 1][a_m] = av.y;
        As[a_k4 + 2][a_m] = av.z;
        As[a_k4 + 3][a_m] = av.w;
        *(float4*)(&Bs[b_k][b_n4]) = bv;
        __syncthreads();
        #pragma unroll
        for (int kk = 0; kk < 8; ++kk) {
            float4 a0 = *(const float4*)(&As[kk][tr * 8]);
            float4 a1 = *(const float4*)(&As[kk][tr * 8 + 4]);
            float4 b0 = *(const float4*)(&Bs[kk][tc * 8]);
            float4 b1 = *(const float4*)(&Bs[kk][tc * 8 + 4]);
            float avv[8] = {a0.x, a0.y, a0.z, a0.w, a1.x, a1.y, a1.z, a1.w};
            float bvv[8] = {b0.x, b0.y, b0.z, b0.w, b1.x, b1.y, b1.z, b1.w};
            #pragma unroll
            for (int i = 0; i < 8; ++i)
                #pragma unroll
                for (int j = 0; j < 8; ++j)
                    acc[i][j] += avv[i] * bvv[j];
        }
    }

    float bv8[8];
    *(float4*)(bv8)     = *(const float4*)(bias + n0 + tc * 8);
    *(float4*)(bv8 + 4) = *(const float4*)(bias + n0 + tc * 8 + 4);

    #pragma unroll
    for (int i = 0; i < 8; ++i) {
        const int m = m0 + tr * 8 + i;
        const int b = m >> 7;
        const int r = m & 127;
        float* outp = gates + ((size_t)r * Bq + b) * G4q + n0 + tc * 8;
        float4 v0 = {acc[i][0] + bv8[0], acc[i][1] + bv8[1],
                     acc[i][2] + bv8[2], acc[i][3] + bv8[3]};
        float4 v1 = {acc[i][4] + bv8[4], acc[i][5] + bv8[5],
                     acc[i][6] + bv8[6], acc[i][7] + bv8[7]};
        *(float4*)outp       = v0;
        *(float4*)(outp + 4) = v1;
    }
}

// ---------------------------------------------------------------------------
// R4/R5 scan: hand-rolled grid barrier + targeted coherence (no grid.sync,
// no L2 wbinv per step). 256 blocks x 512 threads, block owns cells j0..j0+3.
//
// Work mapping: thread (kg = lane 0..63, bg = wave 0..7) covers
// k in [16kg,16kg+16) x b in [4bg,4bg+4): each h element loaded exactly once
// grid-wide, straight into registers via coherent (sc0 sc1) dwordx4 loads.
// Whh in LDS (R1 win), swizzled: Wlds[((k&15)*64 + (k>>4))*4 + slot],
// slot = (s + (kg>>1))&3 -> each 8-lane b128 group touches all 32 banks once.
//
// Reduction: full-wave recursive halving (6 rounds); lane L ends holding the
// fully-reduced gate partial for v = bitrev6(L) -> (bi, ct, jj). 3 shfls
// gather the ct-quad; c replicated across the quad so no further comm.
//
// h(t+1) published with agent-scope relaxed atomic stores (write-through);
// __syncthreads() drains vmcnt before tid0 runs a two-level MONOTONIC arrive
// barrier (16 padded group counters -> root -> generation word, relaxed agent
// atomics, no resets, no cache maintenance). Counters pre-zeroed by gemm.
//
// R5 safety valve: the generation spin is BOUNDED (2^20 sleep-polls ~28 ms).
// A broken barrier now produces a wrong answer + counters instead of a hung
// container. Never hit if the protocol is correct.
// ---------------------------------------------------------------------------
__global__ __launch_bounds__(512, 2)
void lstm_scan(const float* __restrict__ gates,
               const float* __restrict__ Whh,
               float* __restrict__ hbuf,     // [2][H][B] transposed, dbuf
               float* __restrict__ cstate,   // [B][H]
               float* __restrict__ y,        // [B][S][H]
               unsigned int* __restrict__ bar,
               int t0)
{
    __shared__ float4 Wlds[4096];   // 64 KB

    const int tid  = threadIdx.x;
    const int lane = tid & 63;
    const int bg   = tid >> 6;      // wave = batch group (4 batches)
    const int j0   = blockIdx.x * 4;
    const int kg   = lane;          // k-group (16 k's)

    // --- stage Whh cols {s*Hq + j0 .. +4} into swizzled LDS (once) ---
    #pragma unroll
    for (int idx = tid; idx < 4096; idx += 512) {
        const int k  = idx >> 2;
        const int s  = idx & 3;
        const int kgs = k >> 4;
        const int slot = (s + (kgs >> 1)) & 3;
        Wlds[(((k & 15) * 64 + kgs) << 2) + slot] =
            *(const float4*)(Whh + (size_t)k * G4q + s * Hq + j0);
    }

    // lane roles from the bit-reversed reduction mapping: v = bitrev6(lane)
    const int bi = ((lane & 1) << 1) | ((lane >> 1) & 1);        // v[5:4]
    const int ct = (((lane >> 2) & 1) << 1) | ((lane >> 3) & 1); // v[3:2]
    const int jj = (((lane >> 4) & 1) << 1) | ((lane >> 5) & 1); // v[1:0]
    const int b  = bg * 4 + bi;
    const int j  = j0 + jj;

    float creg = cstate[b * Hq + j];
    const float* gbase = gates + (size_t)b * G4q + j;

    __syncthreads();

    for (int tt = 0; tt < CHUNKq; ++tt) {
        const float* ht = hbuf + (tt & 1) * BHq;
        float* hw = hbuf + ((tt + 1) & 1) * BHq;

        // gate pre-loads (plain cached loads; gates is stable this dispatch)
        const float* gp = gbase + (size_t)tt * Bq * G4q;
        const float g0 = gp[0];
        const float g1 = gp[Hq];
        const float g2 = gp[2 * Hq];
        const float g3 = gp[3 * Hq];

        // --- coherent h loads: 16 x dwordx4, one wait ---
        float4 hv[16];
        const float* hp = ht + kg * 16 * Bq + bg * 4;
        #pragma unroll
        for (int i = 0; i < 16; ++i) {
            asm volatile("global_load_dwordx4 %0, %1, off offset:%c2 sc0 sc1"
                         : "=v"(hv[i]) : "v"(hp), "n"(i * 128));
        }
        asm volatile("s_waitcnt vmcnt(0)" ::: "memory");
        __builtin_amdgcn_sched_barrier(0);

        // --- partials: work[bb*16 + s*4 + jjc] over this thread's 16 k ---
        float work[64];
        #pragma unroll
        for (int v = 0; v < 64; ++v) work[v] = 0.f;

        const float4* wrow = Wlds + (kg << 2);
        #pragma unroll
        for (int i = 0; i < 16; ++i) {
            const float4 h4 = hv[i];
            const float4* wr = wrow + i * 256;
            #pragma unroll
            for (int s = 0; s < 4; ++s) {
                const int slot = (s + (kg >> 1)) & 3;
                const float4 w4 = wr[slot];
                #pragma unroll
                for (int bb = 0; bb < 4; ++bb) {
                    const float hb = (bb == 0) ? h4.x : (bb == 1) ? h4.y
                                   : (bb == 2) ? h4.z : h4.w;
                    work[bb * 16 + s * 4 + 0] += hb * w4.x;
                    work[bb * 16 + s * 4 + 1] += hb * w4.y;
                    work[bb * 16 + s * 4 + 2] += hb * w4.z;
                    work[bb * 16 + s * 4 + 3] += hb * w4.w;
                }
            }
        }

        // --- full-wave recursive-halving reduce-scatter (static indices) ---
        #define RR(m, n)                                                     \
        {                                                                    \
            const bool hi = (lane & (m)) != 0;                               \
            _Pragma("unroll")                                                \
            for (int i = 0; i < (n); ++i) {                                  \
                const float send = hi ? work[i] : work[i + (n)];             \
                const float got  = __shfl_xor(send, (m), 64);                \
                const float keep = hi ? work[i + (n)] : work[i];             \
                work[i] = keep + got;                                        \
            }                                                                \
        }
        RR(1, 32) RR(2, 16) RR(4, 8) RR(8, 4) RR(16, 2) RR(32, 1)
        #undef RR

        // lane holds reduced partial for (bi, ct, jj); gather the ct-quad
        const float a0 = work[0];
        const float a1 = __shfl_xor(work[0], 8, 64);    // partner ct^1
        const float a2 = __shfl_xor(work[0], 4, 64);    // partner ct^2
        const float a3 = __shfl_xor(work[0], 12, 64);   // partner ct^3
        #define SEL(p) (((ct ^ (p)) == 0) ? a0 : ((ct ^ (p)) == 1) ? a1 \
                      : ((ct ^ (p)) == 2) ? a2 : a3)
        const float gi = g0 + SEL(0);
        const float gf = g1 + SEL(1);
        const float gg = g2 + SEL(2);
        const float go = g3 + SEL(3);
        #undef SEL

        const float iv = 1.f / (1.f + expf(-gi));
        const float fv = 1.f / (1.f + expf(-gf));
        const float gv = tanhf(gg);
        const float ov = 1.f / (1.f + expf(-go));
        creg = fv * creg + iv * gv;                     // replicated x4 lanes
        const float hval = ov * tanhf(creg);

        if ((lane & 12) == 0) {                         // ct == 0 lanes
            __hip_atomic_store(hw + j * Bq + b, hval,
                               __ATOMIC_RELAXED, __HIP_MEMORY_SCOPE_AGENT);
            y[((size_t)b * Sq + (t0 + tt)) * Hq + j] = hval;
        }

        // --- grid barrier: drain stores, two-level monotonic arrive ---
        __syncthreads();   // emits s_waitcnt vmcnt(0) before s_barrier
        if (tid == 0) {
            const int gid = blockIdx.x >> 4;
            unsigned int old = __hip_atomic_fetch_add(bar + gid * 32, 1u,
                                  __ATOMIC_RELAXED, __HIP_MEMORY_SCOPE_AGENT);
            if ((old & 15u) == 15u) {
                unsigned int r = __hip_atomic_fetch_add(bar + 16 * 32, 1u,
                                  __ATOMIC_RELAXED, __HIP_MEMORY_SCOPE_AGENT);
                if ((r & 15u) == 15u)
                    __hip_atomic_store(bar + 17 * 32, (unsigned int)(tt + 1),
                                  __ATOMIC_RELAXED, __HIP_MEMORY_SCOPE_AGENT);
            }
            unsigned int guard = 0;
            while (__hip_atomic_load(bar + 17 * 32, __ATOMIC_RELAXED,
                                     __HIP_MEMORY_SCOPE_AGENT)
                       < (unsigned int)(tt + 1)
                   && ++guard < (1u << 20))
                __builtin_amdgcn_s_sleep(1);
        }
        __syncthreads();
    }

    if ((lane & 12) == 0) cstate[b * Hq + j] = creg;
}

// ---------------------------------------------------------------------------
// tiny state-layout shims: [B][H] <-> transposed [H][B]
// ---------------------------------------------------------------------------
__global__ __launch_bounds__(256)
void h_to_t(const float* __restrict__ src, float* __restrict__ dst) {
    const int i = blockIdx.x * 256 + threadIdx.x;
    const int b = i >> 10, j = i & 1023;
    dst[j * Bq + b] = src[i];
}
__global__ __launch_bounds__(256)
void h_from_t(const float* __restrict__ src, float* __restrict__ dst) {
    const int i = blockIdx.x * 256 + threadIdx.x;
    const int b = i >> 10, j = i & 1023;
    dst[i] = src[j * Bq + b];
}

// ---------------------------------------------------------------------------
extern "C" void kernel_launch(void* const* d_in, const int* in_sizes, int n_in,
                              void* d_out, int out_size, void* d_ws, size_t ws_size,
                              hipStream_t stream)
{
    const float* x    = (const float*)d_in[0];
    const float* h0   = (const float*)d_in[1];
    const float* c0   = (const float*)d_in[2];
    const float* wih0 = (const float*)d_in[3];
    const float* whh0 = (const float*)d_in[4];
    const float* b0   = (const float*)d_in[5];
    const float* wih1 = (const float*)d_in[6];
    const float* whh1 = (const float*)d_in[7];
    const float* b1   = (const float*)d_in[8];

    float* out = (float*)d_out;
    float* y1  = out;                                  // [B,S,H]
    float* hn  = out + (size_t)Bq * Sq * Hq;           // [2,B,H]
    float* cn  = hn + 2 * BHq;                         // [2,B,H]

    float* ws    = (float*)d_ws;
    float* gates = ws;                                  // CHUNK*B*4H floats
    float* hbuf  = gates + (size_t)CHUNKq * Bq * G4q;   // 2*B*H
    float* cst   = hbuf + 2 * BHq;                      // B*H
    unsigned int* bar = (unsigned int*)(cst + BHq);     // 18*32 uints

    // y0 aliases the y1 output region (chunk-ordered reads-before-writes).
    float* y0 = y1;

    for (int l = 0; l < 2; ++l) {
        const float* Ain  = l ? y0   : x;
        const float* wih  = l ? wih1 : wih0;
        const float* whh  = l ? whh1 : whh0;
        const float* bias = l ? b1   : b0;
        float* yout       = l ? y1   : y0;

        h_to_t<<<128, 256, 0, stream>>>(h0 + (size_t)l * BHq, hbuf);
        hipMemcpyAsync(cst, c0 + (size_t)l * BHq, BHq * sizeof(float),
                       hipMemcpyDeviceToDevice, stream);

        for (int ch = 0; ch < NCHq; ++ch) {
            const int s0 = ch * CHUNKq;
            gemm_xproj<<<dim3(32, 32), 256, 0, stream>>>(Ain, wih, bias,
                                                         gates, bar, s0);

            const float* garg = gates;
            const float* warg = whh;
            float* harg = hbuf;
            float* carg = cst;
            float* yarg = yout;
            unsigned int* barg = bar;
            int targ = s0;
            void* kp[] = {(void*)&garg, (void*)&warg, (void*)&harg,
                          (void*)&carg, (void*)&yarg, (void*)&barg,
                          (void*)&targ};
            hipLaunchCooperativeKernel((void*)lstm_scan, dim3(256), dim3(512),
                                       kp, 0, stream);
        }

        h_from_t<<<128, 256, 0, stream>>>(hbuf, hn + (size_t)l * BHq);
        hipMemcpyAsync(cn + (size_t)l * BHq, cst, BHq * sizeof(float),
                       hipMemcpyDeviceToDevice, stream);
    }
}